// Round 1
// 641.364 us; speedup vs baseline: 1.0578x; 1.0578x over previous
//
#include <hip/hip_runtime.h>
#include <cstdint>
#include <cstddef>

typedef __attribute__((ext_vector_type(8))) short bf16x8;   // MFMA A/B frag (4 VGPRs)
typedef __attribute__((ext_vector_type(16))) float f32x16;  // MFMA C/D (16 VGPRs)

__device__ __forceinline__ unsigned short f2bf(float f) {   // fp32 -> bf16 RNE
    unsigned int u = __builtin_bit_cast(unsigned int, f);
    u += 0x7fffu + ((u >> 16) & 1u);
    return (unsigned short)(u >> 16);
}

// packed fp32x2 -> bf16x2 (HW v_cvt_pk_bf16_f32 on gfx950 when available)
__device__ __forceinline__ unsigned int pk2(float a, float b) {
#if __has_builtin(__builtin_amdgcn_cvt_pk_bf16_f32)
    auto r = __builtin_amdgcn_cvt_pk_bf16_f32(a, b);
    return __builtin_bit_cast(unsigned int, r);
#else
    return (unsigned int)f2bf(a) | ((unsigned int)f2bf(b) << 16);
#endif
}

template<int CTRL>
__device__ __forceinline__ float dpp_add(float v) {
    int t = __builtin_amdgcn_update_dpp(0, __builtin_bit_cast(int, v), CTRL, 0xf, 0xf, true);
    return v + __builtin_bit_cast(float, t);
}
// row_shr:1=0x111 :2=0x112 :4=0x114 :8=0x118 ; row_bcast15=0x142 ; row_ror:8=0x128

__device__ __forceinline__ float swz16_add(float v) {   // v += lane^16 partner
    int t = __builtin_amdgcn_ds_swizzle(__builtin_bit_cast(int, v), 0x401F);
    return v + __builtin_bit_cast(float, t);
}

__device__ __forceinline__ float fast_tanh(float x) {
    float e = __expf(2.0f * x);
    return 1.0f - 2.0f / (e + 1.0f);
}

// ---------------- prep: W1t[128][128], W2t[128][208] bf16, [n][k] ----------------
// W2t k-layout: k' 0..99 = W2 rows 0..99 (x), 100..103 = 0, 104..203 = W2 rows
// 100..199 (msg), 204..207 = 0  -> 13 frag-blocks of 16 with a clean hi-half split.
__global__ void prep_kernel(const float* __restrict__ W1, const float* __restrict__ W2,
                            unsigned short* __restrict__ W1t, unsigned short* __restrict__ W2t)
{
    int idx = blockIdx.x * 256 + threadIdx.x;
    if (idx < 128 * 128) {
        int nn = idx >> 7, kk = idx & 127;
        W1t[idx] = (nn < 100 && kk < 100) ? f2bf(W1[kk * 100 + nn]) : (unsigned short)0;
    } else {
        int j = idx - 128 * 128;
        if (j < 128 * 208) {
            int nn = j / 208, kk = j - nn * 208;
            unsigned short v = 0;
            if (nn < 100) {
                if (kk < 100) v = f2bf(W2[kk * 100 + nn]);
                else if (kk >= 104 && kk < 204) v = f2bf(W2[(kk - 4) * 100 + nn]);
            }
            W2t[j] = v;
        }
    }
}

// ---------------- fused kernel: attention (32 nodes) + 2-layer MLP ----------------
// LDS budget is the occupancy governor: 22720 B declared -> 7 blocks/CU, so the
// whole 1563-block grid is co-resident in ONE scheduling round (at 5 blocks/CU the
// grid ran as 2 rounds with round 2 only 22% full -> ~61% machine utilization).
#define HP 104   // h_s / msg_s pitch (ushorts); 100 real + 4 zero pad

__global__ __launch_bounds__(256) void fused_kernel(
    const int* __restrict__ nodes, const int* __restrict__ nei,
    const float* __restrict__ wei, const float* __restrict__ s_vec,
    const float* __restrict__ emb, const float* __restrict__ W1,
    const float* __restrict__ b1, const float* __restrict__ q1,
    const unsigned short* __restrict__ W1t, const unsigned short* __restrict__ W2t,
    const float* __restrict__ b2, float* __restrict__ out, int N)
{
    // h_s: neighbor rows [32][104] bf16 (attn) -> x rows (layer)
    // hst: hs=h*s, k-block-tiled [14 blocks][32 rows][8 ushorts] (conflict-free b128)
    // msg_s: per-node attention messages, bf16, persists into the layer phase
    // part2: 4 slots (one per wave, full in-wave k-reduction done via butterfly)
    __shared__ __align__(16) unsigned short h_s[32 * HP];     // 6656 B
    __shared__ __align__(16) unsigned short hst[14 * 32 * 8]; // 7168 B
    __shared__ __align__(16) unsigned short msg_s[32 * HP];   // 6656 B
    __shared__ __align__(16) float part2[4 * 100];            // 1600 B
    __shared__ __align__(16) float spart[128];                // 512 B
    __shared__ __align__(16) float wei_s[32];                 // 128 B

    const int tid  = threadIdx.x;
    const int lane = tid & 63;
    const int w    = tid >> 6;
    const int col  = lane & 31;
    const int hi   = lane >> 5;
    const int n    = w * 32 + col;          // layer-phase output column (>=100 masked)
    const int n0   = blockIdx.x * 32;       // this block's 32 consecutive nodes

    // persistent W1 fragments. These serve as the *A* operand of the transposed
    // score MFMA: by the A/B layout symmetry of mfma_32x32x16 (lane&31 -> own
    // output index, 8*(lane>>5)+e -> K elem) the per-lane data is identical to
    // the old B-operand load.
    bf16x8 Bf1[7];
    #pragma unroll
    for (int ks = 0; ks < 7; ++ks)
        Bf1[ks] = *(const bf16x8*)(W1t + n * 128 + ks * 16 + hi * 8);

    // per-ACC-REG constants: transposed C layout has row n(r) = w*32 + (r&3)+8*(r>>2)+4*hi
    float b1r[16], w100r[16], q1r[16];
    #pragma unroll
    for (int r = 0; r < 16; ++r) {
        int nn = w * 32 + (r & 3) + 8 * (r >> 2) + 4 * hi;
        bool ok = nn < 100;
        b1r[r]   = ok ? b1[nn] : 0.0f;
        w100r[r] = ok ? W1[100 * 100 + nn] : 0.0f;  // W1 row 100 = wei column
        q1r[r]   = ok ? q1[nn] : 0.0f;              // =0 masks padded n in reduction
    }
    const bool nok = (n < 100);

    // zero pads once: hst k>=100 (block 12 hi-half + block 13), h_s/msg_s d 100..103
    if (tid < 32) {
        *(uint2*)&hst[(12 * 32 + tid) * 8 + 4] = make_uint2(0, 0);
        *(uint4*)&hst[(13 * 32 + tid) * 8]     = make_uint4(0, 0, 0, 0);
        *(uint2*)&h_s[tid * HP + 100]          = make_uint2(0, 0);
        *(uint2*)&msg_s[tid * HP + 100]        = make_uint2(0, 0);
    }

    const int gk = tid >> 3;   // staging row 0..31
    const int gj = tid & 7;    // staging float4-lane 0..7
    const bool t24 = (gj == 0);

    // T14 async-stage: emb/s_vec rows for node it live in VGPRs one iteration
    // ahead (nei index prefetched TWO ahead), so gather latency hides under the
    // previous iteration's MFMA/softmax/msg phases instead of stalling the pack.
    float4 h0, h1, h2, h3, s0, s1, s2, s3;
    int   nidx_pf = 0;
    float wv = 0.0f;
    {
        int nid0 = nei[(size_t)n0 * 32 + gk];
        const float4* erow = (const float4*)(emb + (size_t)nid0 * 100);
        const float4* srow = (const float4*)(s_vec + (size_t)n0 * 100);
        h0 = erow[gj];      s0 = srow[gj];
        h1 = erow[gj + 8];  s1 = srow[gj + 8];
        h2 = erow[gj + 16]; s2 = srow[gj + 16];
        if (t24) { h3 = erow[24]; s3 = srow[24]; }
        if (tid < 32) wv = wei[(size_t)n0 * 32 + tid];
        if (n0 + 1 < N) nidx_pf = nei[(size_t)(n0 + 1) * 32 + gk];
    }
    __syncthreads();

    for (int it = 0; it < 32; ++it) {
        const int node = n0 + it;
        if (node >= N) break;              // block-uniform

        // ---- stage from prefetched regs: h_s (bf16) + hst (bf16, tiled, *s)
        if (tid < 32) wei_s[tid] = wv;
        {
            #define ST_C4(c4, h4, s4) { \
                *(uint2*)&h_s[gk * HP + (c4) * 4] = \
                    make_uint2(pk2(h4.x, h4.y), pk2(h4.z, h4.w)); \
                *(uint2*)&hst[(((c4) >> 1) * 32 + gk) * 8 + ((c4) & 1) * 4] = \
                    make_uint2(pk2(h4.x * s4.x, h4.y * s4.y), pk2(h4.z * s4.z, h4.w * s4.w)); }
            ST_C4(gj,      h0, s0)
            ST_C4(gj + 8,  h1, s1)
            ST_C4(gj + 16, h2, s2)
            if (t24) { ST_C4(24, h3, s3) }
            #undef ST_C4
        }
        // ---- issue next node's gather now (consumed at top of it+1)
        if (it + 1 < 32 && node + 1 < N) {
            const float4* erow = (const float4*)(emb + (size_t)nidx_pf * 100);
            const float4* srow = (const float4*)(s_vec + (size_t)(node + 1) * 100);
            h0 = erow[gj];      s0 = srow[gj];
            h1 = erow[gj + 8];  s1 = srow[gj + 8];
            h2 = erow[gj + 16]; s2 = srow[gj + 16];
            if (t24) { h3 = erow[24]; s3 = srow[24]; }
            if (tid < 32) wv = wei[(size_t)(node + 1) * 32 + tid];
            if (it + 2 < 32 && node + 2 < N) nidx_pf = nei[(size_t)(node + 2) * 32 + gk];
        }
        __syncthreads();   // B1

        // ---- TRANSPOSED score matmul: C[row = n (per reg)][col = k (lane&31)]
        // acc init: bias(n) + wei[k]*W1[100][n]
        const float wk = wei_s[col];
        f32x16 acc;
        #pragma unroll
        for (int r = 0; r < 16; ++r) acc[r] = fmaf(wk, w100r[r], b1r[r]);
        #pragma unroll
        for (int ks = 0; ks < 7; ++ks) {
            bf16x8 hfrag = *(const bf16x8*)&hst[((2 * ks + hi) * 32 + col) * 8];
            acc = __builtin_amdgcn_mfma_f32_32x32x16_bf16(Bf1[ks], hfrag, acc, 0, 0, 0);
        }

        // ---- epilogue: sum_n tanh(S)*q1 is now an in-lane reduction over 16 regs
        // (was 16 rows x 5 DPP steps = 160 inst). One shfl merges the hi half.
        float part = 0.0f;
        #pragma unroll
        for (int r = 0; r < 16; ++r) part = fmaf(fast_tanh(acc[r]), q1r[r], part);
        part += __shfl_xor(part, 32);
        if (lane < 32) spart[w * 32 + lane] = part;   // per-wave 32-n partial for k=lane
        __syncthreads();   // B2

        // ---- softmax over k, redundantly per wave (no extra barrier)
        float attk;
        {
            float s = spart[col] + spart[32 + col] + spart[64 + col] + spart[96 + col];
            float mx = s;
            #pragma unroll
            for (int off = 16; off; off >>= 1) mx = fmaxf(mx, __shfl_xor(mx, off));
            float e = __expf(s - mx);
            float den = e;
            #pragma unroll
            for (int off = 16; off; off >>= 1) den += __shfl_xor(den, off);
            float attv = e / den;
            attk = __shfl(attv, w * 8 + (lane >> 3));   // att for my k-row
        }

        // ---- msg partials: full in-wave k-butterfly -> ONE part2 slot per wave
        {
            const int oct  = lane & 7;
            const int krow = w * 8 + (lane >> 3);
            const float a  = attk;
            uint4 r1 = *(const uint4*)&h_s[krow * HP + oct * 8];
            const int oct2 = (oct < 5) ? oct : 4;   // clamped dup, masked at write
            uint4 r2 = *(const uint4*)&h_s[krow * HP + 64 + oct2 * 8];
            float m1[8], m2[8];
            #define UNP2(u, d0, d1) { d0 = __builtin_bit_cast(float, (u) << 16); \
                                      d1 = __builtin_bit_cast(float, (u) & 0xffff0000u); }
            { float t0,t1; UNP2(r1.x,t0,t1); m1[0]=a*t0; m1[1]=a*t1; }
            { float t0,t1; UNP2(r1.y,t0,t1); m1[2]=a*t0; m1[3]=a*t1; }
            { float t0,t1; UNP2(r1.z,t0,t1); m1[4]=a*t0; m1[5]=a*t1; }
            { float t0,t1; UNP2(r1.w,t0,t1); m1[6]=a*t0; m1[7]=a*t1; }
            { float t0,t1; UNP2(r2.x,t0,t1); m2[0]=a*t0; m2[1]=a*t1; }
            { float t0,t1; UNP2(r2.y,t0,t1); m2[2]=a*t0; m2[3]=a*t1; }
            { float t0,t1; UNP2(r2.z,t0,t1); m2[4]=a*t0; m2[5]=a*t1; }
            { float t0,t1; UNP2(r2.w,t0,t1); m2[6]=a*t0; m2[7]=a*t1; }
            #undef UNP2
            #pragma unroll
            for (int j = 0; j < 8; ++j) {   // k ^ 1 (row_ror:8 within 16-lane rows)
                m1[j] = dpp_add<0x128>(m1[j]);
                m2[j] = dpp_add<0x128>(m2[j]);
            }
            #pragma unroll
            for (int j = 0; j < 8; ++j) {   // k ^ 2 (ds_swizzle xor-16)
                m1[j] = swz16_add(m1[j]);
                m2[j] = swz16_add(m2[j]);
            }
            #pragma unroll
            for (int j = 0; j < 8; ++j) {   // k ^ 4 (cross 32-lane halves)
                m1[j] += __shfl_xor(m1[j], 32);
                m2[j] += __shfl_xor(m2[j], 32);
            }
            if ((lane >> 3) == 0) {         // lanes 0..7 hold the full 8-krow sums
                float* p = &part2[w * 100];
                *(float4*)&p[oct * 8]     = make_float4(m1[0], m1[1], m1[2], m1[3]);
                *(float4*)&p[oct * 8 + 4] = make_float4(m1[4], m1[5], m1[6], m1[7]);
                if (oct < 5) *(float4*)&p[64 + oct * 8]     = make_float4(m2[0], m2[1], m2[2], m2[3]);
                if (oct < 4) *(float4*)&p[64 + oct * 8 + 4] = make_float4(m2[4], m2[5], m2[6], m2[7]);
            }
        }
        __syncthreads();   // B4

        // ---- reduce 4 per-wave partials -> msg_s row (bf16), waves 0,1
        if (w < 2) {
            int d = w * 64 + lane;
            if (d < 100) {
                float s = part2[d] + part2[100 + d] + part2[200 + d] + part2[300 + d];
                msg_s[it * HP + d] = f2bf(s);
            }
        }
    }

    // ================= layer phase: x = relu([x,msg]@W2+b2) twice =================
    __syncthreads();   // all attn reads of h_s done; msg_s rows final after B_L1

    // W2 fragments + x-gather (emb[nodes]) -> h_s region
    bf16x8 Bf2[13];
    #pragma unroll
    for (int ks = 0; ks < 13; ++ks)
        Bf2[ks] = *(const bf16x8*)(W2t + n * 208 + ks * 16 + hi * 8);
    const float b2v = nok ? b2[n] : 0.0f;
    {
        int row = n0 + gk;
        int rc = row < N ? row : N - 1;
        const float4* xr = (const float4*)(emb + (size_t)nodes[rc] * 100);
        float4 x0 = xr[gj], x1 = xr[gj + 8], x2 = xr[gj + 16];
        float4 x3;
        if (t24) x3 = xr[24];
        *(uint2*)&h_s[gk * HP + gj * 4]        = make_uint2(pk2(x0.x, x0.y), pk2(x0.z, x0.w));
        *(uint2*)&h_s[gk * HP + (gj + 8) * 4]  = make_uint2(pk2(x1.x, x1.y), pk2(x1.z, x1.w));
        *(uint2*)&h_s[gk * HP + (gj + 16) * 4] = make_uint2(pk2(x2.x, x2.y), pk2(x2.z, x2.w));
        if (t24)
            *(uint2*)&h_s[gk * HP + 96]        = make_uint2(pk2(x3.x, x3.y), pk2(x3.z, x3.w));
    }
    __syncthreads();   // B_L1

    // A-frag address: k' blocks 0..12 -> h_s, 13..25 -> msg_s (ks=6 splits on hi)
    #define AFRAG(ks) (*(const bf16x8*)( \
        (ks) < 6  ? &h_s[col * HP + (ks) * 16 + hi * 8] : \
        (ks) == 6 ? (hi ? &msg_s[col * HP] : &h_s[col * HP + 96]) : \
                    &msg_s[col * HP + (ks) * 16 + hi * 8 - 104]))

    f32x16 acc;
    #pragma unroll
    for (int r = 0; r < 16; ++r) acc[r] = b2v;
    #pragma unroll
    for (int ks = 0; ks < 13; ++ks)
        acc = __builtin_amdgcn_mfma_f32_32x32x16_bf16(AFRAG(ks), Bf2[ks], acc, 0, 0, 0);
    __syncthreads();   // B_L2: pass-1 reads done
    if (nok) {
        #pragma unroll
        for (int r = 0; r < 16; ++r) {
            int m = (r & 3) + 8 * (r >> 2) + 4 * hi;
            h_s[m * HP + n] = f2bf(fmaxf(acc[r], 0.0f));
        }
    }
    __syncthreads();   // B_L3

    f32x16 acc2;
    #pragma unroll
    for (int r = 0; r < 16; ++r) acc2[r] = b2v;
    #pragma unroll
    for (int ks = 0; ks < 13; ++ks)
        acc2 = __builtin_amdgcn_mfma_f32_32x32x16_bf16(AFRAG(ks), Bf2[ks], acc2, 0, 0, 0);
    #undef AFRAG
    if (nok) {
        #pragma unroll
        for (int r = 0; r < 16; ++r) {
            int m = (r & 3) + 8 * (r >> 2) + 4 * hi;
            int row = n0 + m;
            if (row < N) out[(size_t)row * 100 + n] = fmaxf(acc2[r], 0.0f);
        }
    }
}

// ---------------- launch ----------------
extern "C" void kernel_launch(void* const* d_in, const int* in_sizes, int n_in,
                              void* d_out, int out_size, void* d_ws, size_t ws_size,
                              hipStream_t stream) {
    const int*   nodes = (const int*)d_in[0];
    const int*   nei   = (const int*)d_in[1];
    const float* wei   = (const float*)d_in[2];
    const float* s_vec = (const float*)d_in[3];
    const float* emb   = (const float*)d_in[4];
    const float* W1    = (const float*)d_in[5];
    const float* b1    = (const float*)d_in[6];
    const float* q1    = (const float*)d_in[7];
    const float* W2    = (const float*)d_in[8];
    const float* b2    = (const float*)d_in[9];
    float* out = (float*)d_out;
    const int N = in_sizes[0];

    unsigned short* W1t = (unsigned short*)d_ws;       // 128*128*2 = 32 KB
    unsigned short* W2t = W1t + 128 * 128;             // 128*208*2 = 52 KB

    prep_kernel<<<168, 256, 0, stream>>>(W1, W2, W1t, W2t);
    const int gB = (N + 31) / 32;
    fused_kernel<<<gB, 256, 0, stream>>>(nodes, nei, wei, s_vec, emb, W1, b1, q1,
                                         W1t, W2t, b2, out, N);
}